// Round 1
// baseline (312.330 us; speedup 1.0000x reference)
//
#include <hip/hip_runtime.h>

// Green-Ampt infiltration scan.
// B=16384 independent rows, T=2048 sequential steps per row.
// One thread per row; float4 streaming with register double-buffer prefetch.

#define GA_DT 1.0f
#define GA_MIN_INF 0.1f
#define GA_EPS 1e-6f

constexpr int BATCH = 8; // float4 chunks prefetched per batch = 32 elements

__global__ __launch_bounds__(64, 1) void ga_scan_kernel(
    const float* __restrict__ precip,
    const float* __restrict__ K,
    const float* __restrict__ psi,
    const float* __restrict__ dtheta,
    float* __restrict__ out,
    int B, int T) {
  int b = blockIdx.x * 64 + threadIdx.x;
  if (b >= B) return;

  const float Kv = K[b];
  const float pd = psi[b] * dtheta[b];

  const size_t rowoff = (size_t)b * (size_t)T;
  const float4* __restrict__ pr = reinterpret_cast<const float4*>(precip + rowoff);
  float4* __restrict__ o_infil  = reinterpret_cast<float4*>(out + rowoff);
  float4* __restrict__ o_runoff = reinterpret_cast<float4*>(out + (size_t)B * (size_t)T + rowoff);
  float4* __restrict__ o_cumF   = reinterpret_cast<float4*>(out + 2ull * (size_t)B * (size_t)T + rowoff);

  const int nchunk = T >> 2;        // float4 chunks per row
  const int nb = nchunk / BATCH;    // batches per row (T=2048 -> 64)

  float F = 0.0f;

  float4 buf[BATCH];
#pragma unroll
  for (int i = 0; i < BATCH; ++i) buf[i] = pr[i];

  auto process = [&](const float4* bptr, int kb) {
#pragma unroll
    for (int i = 0; i < BATCH; ++i) {
      const float4 p = bptr[i];
      float pv[4] = {p.x, p.y, p.z, p.w};
      float fiv[4], rov[4], cfv[4];
#pragma unroll
      for (int j = 0; j < 4; ++j) {
        float fcap = fmaxf(Kv * (1.0f + pd / fmaxf(F, GA_EPS)), GA_MIN_INF);
        float fact = fminf(pv[j], fcap);
        float ro   = fmaxf(pv[j] - fact, 0.0f);
        F = F + fact * GA_DT;
        fiv[j] = fact;
        rov[j] = ro;
        cfv[j] = F;
      }
      const int idx = kb * BATCH + i;
      o_infil[idx]  = make_float4(fiv[0], fiv[1], fiv[2], fiv[3]);
      o_runoff[idx] = make_float4(rov[0], rov[1], rov[2], rov[3]);
      o_cumF[idx]   = make_float4(cfv[0], cfv[1], cfv[2], cfv[3]);
    }
  };

  int kb = 0;
  for (; kb < nb - 1; ++kb) {
    float4 nxt[BATCH];
#pragma unroll
    for (int i = 0; i < BATCH; ++i) nxt[i] = pr[(kb + 1) * BATCH + i];
    process(buf, kb);
#pragma unroll
    for (int i = 0; i < BATCH; ++i) buf[i] = nxt[i];
  }
  process(buf, nb - 1);
}

extern "C" void kernel_launch(void* const* d_in, const int* in_sizes, int n_in,
                              void* d_out, int out_size, void* d_ws, size_t ws_size,
                              hipStream_t stream) {
  const float* precip = (const float*)d_in[0];
  const float* K      = (const float*)d_in[1];
  const float* psi    = (const float*)d_in[2];
  const float* dtheta = (const float*)d_in[3];
  float* out = (float*)d_out;

  const int B = in_sizes[1];            // K has B elements
  const int T = in_sizes[0] / B;        // precip is B*T

  const int block = 64;
  const int grid = (B + block - 1) / block;
  ga_scan_kernel<<<grid, block, 0, stream>>>(precip, K, psi, dtheta, out, B, T);
}